// Round 13
// baseline (3471.347 us; speedup 1.0000x reference)
//
#include <hip/hip_runtime.h>
#include <stdint.h>

#define B_ 64
#define T_ 512
#define I_ 256
#define H_ 512
#define NTHR_ 512
#define D_ 8   // ring depth in CYC fallback mode

typedef __attribute__((ext_vector_type(8))) short short8;
typedef __attribute__((ext_vector_type(4))) float float4v;
typedef __attribute__((ext_vector_type(4))) unsigned int uint4v;
typedef __attribute__((ext_vector_type(2))) unsigned int uint2v;

static_assert(sizeof(short8) == 16, "");

// tile = 2KB: hi plane 1KB = [jh][lane'][8B] (2 x 512B), lo plane same at +1KB.
// Writer block a fills [jh=(a>>2)&1][lane'=16*(a&3)+m] for m=0..15 -> one FULL
// 128B line per plane (no partial-line RMW at MALL/HBM). Reader lane l takes
// jh0 8B at l*8 and jh1 8B at 512+l*8.
#define TILE_B 2048
#define SLOT_B ((size_t)4 * 16 * TILE_B)  // 128 KB per slot

// ---- bf16 helpers (round-to-nearest-even) ----
__device__ __forceinline__ unsigned short f2bf(float x) {
  union { float f; uint32_t u; } v; v.f = x;
  uint32_t r = v.u + 0x7FFFu + ((v.u >> 16) & 1u);
  return (unsigned short)(r >> 16);
}
__device__ __forceinline__ float bf2f(unsigned short h) {
  union { uint32_t u; float f; } v; v.u = ((uint32_t)h) << 16; return v.f;
}
__device__ __forceinline__ void splitHL(float x, unsigned short& hi, unsigned short& lo) {
  hi = f2bf(x);
  lo = f2bf(x - bf2f(hi));   // x - hi is exact in fp32
}

// byte offset of a (slot,bg,ktile) tile
__device__ __forceinline__ size_t rbyte(int slot, int bg, int ht) {
  return ((size_t)slot * 64 + bg * 16 + ht) * TILE_B;
}

// per-thread spin on one progress word (bypass load)
__device__ __forceinline__ void wait_ge(const uint32_t* p, int tgt) {
  if (tgt <= 0) return;
  int it = 0;
  while ((int)__hip_atomic_load(p, __ATOMIC_RELAXED, __HIP_MEMORY_SCOPE_AGENT) < tgt) {
    __builtin_amdgcn_s_sleep(1);
    if (++it > 2000000) break;   // safety: degrade to wrong answer, never hang
  }
}

__device__ __forceinline__ short8 mk8(uint2v a, uint2v b) {
  union { uint32_t u[4]; short8 s; } t;
  t.u[0] = a[0]; t.u[1] = a[1]; t.u[2] = b[0]; t.u[3] = b[1];
  return t.s;
}

#define MFMA16(A, Bv, C) __builtin_amdgcn_mfma_f32_16x16x32_bf16(A, Bv, C, 0, 0, 0)

// counted wait on our asm-issued vmem + scheduling fence (rule #18)
#define WAITV(n) do { \
    asm volatile("s_waitcnt vmcnt(" #n ")" ::: "memory"); \
    __builtin_amdgcn_sched_barrier(0); \
  } while (0)

// One LSTM layer, persistent. 8 waves/block: (bg 0..3) x (kh 0..1), split-K.
// Block 'a' owns h-cols [4a,4a+4) -> 16 gate cols. K: [0,K1)=inp, [K1,K1+512)=h.
// MFMA frags: k(q,j)=4q+(j&3)+16*(j>>2); A-row=lane&15, B-col=lane&15,
// C/D col=lane&15 row=4*(lane>>4)+i (m89-verified).
// Round-13 change (single): full-line ring writes via [jh][lane'] planes.
// Everything else = round-12 (proven ~3.0-3.1ms structure).
template <int LAYER, bool FULL>
__device__ void run_layer(
    int a,
    const float* __restrict__ x,
    const float* __restrict__ Wxp, const float* __restrict__ bxp,
    const float* __restrict__ Whp,
    uint32_t* prog0, uint32_t* prog1,
    uint8_t* r0, uint8_t* r1,
    float* h1f,
    unsigned short* Wsh, float* red)
{
  constexpr int K1 = LAYER ? H_ : I_;
  constexpr int NT = (K1 + H_) / 32;   // 24 (L0) or 32 (L1) K-tiles
  constexpr int NTT = NT / 2;          // 12 or 16 tiles per k-half wavegroup
  const int tid = threadIdx.x;
  const int lane = tid & 63;
  const int wid = tid >> 6;     // 0..7
  const int bg = wid & 3;       // batch group (16 batches)
  const int kh = wid >> 2;      // K-half (tile parity)
  const int qq = lane >> 4;
  const int cc = lane & 15;
  const int brow = bg * 16 + cc;

  // ---- stage weight slice: pass0 = LO (pulled to regs), pass1 = HI (stays in LDS) ----
  short8 wlo[NTT];
  for (int pass = 0; pass < 2; ++pass) {
    for (int idx = tid; idx < NT * 512; idx += NTHR_) {
      int tile = idx >> 9, r = idx & 511, ln = r >> 3, j = r & 7;
      int k = tile * 32 + 4 * (ln >> 4) + (j & 3) + 16 * (j >> 2);
      int n = 4 * a + (ln & 3);
      int g = (ln & 15) >> 2;
      float wvv = (k < K1) ? Wxp[((size_t)g * K1 + k) * H_ + n]
                           : Whp[((size_t)g * H_ + (k - K1)) * H_ + n];
      unsigned short hi, lo; splitHL(wvv, hi, lo);
      Wsh[idx] = pass ? hi : lo;
    }
    __syncthreads();
    if (pass == 0) {
      #pragma unroll
      for (int tt = 0; tt < NTT; ++tt) {
        int tile = 2 * tt + kh;
        wlo[tt] = *(const short8*)(Wsh + tile * 512 + lane * 8);
      }
      __syncthreads();   // all pulled before HI overwrites
    }
  }

  const float biasv = bxp[(size_t)(cc >> 2) * H_ + 4 * a + (cc & 3)];
  float cst[4] = {0.f, 0.f, 0.f, 0.f};

  uint32_t* myprog = LAYER ? prog1 : prog0;
  const bool ownw = FULL ? ((tid & 127) == a) : false;

  for (int t = 0; t < T_; ++t) {
    const int slotP = FULL ? t       : (t & (D_ - 1));        // h[t-1]
    const int slotC = FULL ? (t + 1) : ((t + 1) & (D_ - 1));  // h[t]
    const float bv = (kh == 0) ? biasv : 0.f;   // bias only in kh0 (split-K sums halves)
    float4v accA = {bv, bv, bv, bv};              // hi*Whi (+bias in kh0)
    float4v accB = {0.f, 0.f, 0.f, 0.f};          // lo*Whi
    float4v accC = {0.f, 0.f, 0.f, 0.f};          // hi*Wlo

    uint2v h0b[8], h1b[8], l0b[8], l1b[8];   // per-tile jh0/jh1 hi/lo 8B chunks

    auto issue_ring = [&](int tt) {
      const int tile = 2 * tt + kh;
      const uint8_t* p;
      if (!LAYER)         p = r0 + rbyte(slotP, bg, tile - 8);
      else if (tile < 16) p = r0 + rbyte(slotC, bg, tile);
      else                p = r1 + rbyte(slotP, bg, tile - 16);
      p += (size_t)lane * 8;
      const int s = tt & 7;
      if constexpr (FULL) {
        asm volatile("global_load_dwordx2 %0, %4, off\n\t"
                     "global_load_dwordx2 %1, %4, off offset:512\n\t"
                     "global_load_dwordx2 %2, %4, off offset:1024\n\t"
                     "global_load_dwordx2 %3, %4, off offset:1536"
                     : "=&v"(h0b[s]), "=&v"(h1b[s]), "=&v"(l0b[s]), "=&v"(l1b[s])
                     : "v"(p) : "memory");
      } else {
        asm volatile("global_load_dwordx2 %0, %4, off sc0 sc1\n\t"
                     "global_load_dwordx2 %1, %4, off offset:512 sc0 sc1\n\t"
                     "global_load_dwordx2 %2, %4, off offset:1024 sc0 sc1\n\t"
                     "global_load_dwordx2 %3, %4, off offset:1536 sc0 sc1"
                     : "=&v"(h0b[s]), "=&v"(h1b[s]), "=&v"(l0b[s]), "=&v"(l1b[s])
                     : "v"(p) : "memory");
      }
    };
    auto proc_ring = [&](int tt) {
      const int tile = 2 * tt + kh;
      const int s = tt & 7;
      short8 h = mk8(h0b[s], h1b[s]);
      short8 l = mk8(l0b[s], l1b[s]);
      short8 bhi = *(const short8*)(Wsh + tile * 512 + lane * 8);
      accA = MFMA16(h, bhi, accA);
      accB = MFMA16(l, bhi, accB);
      accC = MFMA16(h, wlo[tt], accC);
    };

    if constexpr (!LAYER) {
      uint4v xw0[4], xw1[4];
      #pragma unroll
      for (int u = 0; u < 4; ++u) {        // x tiles 2u+kh (read-only: cached)
        const float* xp = x + ((size_t)brow * T_ + t) * I_ + (2 * u + kh) * 32 + 4 * qq;
        asm volatile("global_load_dwordx4 %0, %2, off\n\t"
                     "global_load_dwordx4 %1, %2, off offset:64"
                     : "=&v"(xw0[u]), "=&v"(xw1[u]) : "v"(xp) : "memory");
      }
      if constexpr (FULL) {
        if (!ownw) wait_ge(&prog0[tid], t);
      } else {
        if (tid < 128)      wait_ge(&prog0[tid], t);
        else if (tid < 256) wait_ge(&prog1[tid - 128], t - (D_ - 1));
      }
      __syncthreads();                     // poll's atomic load drained x too
      #pragma unroll
      for (int tt = 4; tt < 12; ++tt) issue_ring(tt);   // 32 loads
      #pragma unroll
      for (int u = 0; u < 4; ++u) {        // convert+MFMA x under ring flight
        short8 ahi, alo;
        #pragma unroll
        for (int j = 0; j < 4; ++j) {
          unsigned short hh, ll;
          splitHL(__uint_as_float(xw0[u][j]), hh, ll); ahi[j] = (short)hh; alo[j] = (short)ll;
          splitHL(__uint_as_float(xw1[u][j]), hh, ll); ahi[j + 4] = (short)hh; alo[j + 4] = (short)ll;
        }
        const int tile = 2 * u + kh;
        short8 bhi = *(const short8*)(Wsh + tile * 512 + lane * 8);
        accA = MFMA16(ahi, bhi, accA);
        accB = MFMA16(alo, bhi, accB);
        accC = MFMA16(ahi, wlo[u], accC);
      }
      WAITV(16);                           // tiles 4..7 landed
      proc_ring(4); proc_ring(5); proc_ring(6); proc_ring(7);
      WAITV(0);
      proc_ring(8); proc_ring(9); proc_ring(10); proc_ring(11);
    } else {
      if constexpr (FULL) {
        // split poll: h0 half first (L0 ahead -> ~instant), then own-layer wait
        wait_ge(&prog0[tid], t + 1);
        __syncthreads();
        #pragma unroll
        for (int tt = 0; tt < 8; ++tt) issue_ring(tt);   // 32 loads
        WAITV(16);
        proc_ring(0); proc_ring(1); proc_ring(2); proc_ring(3);
        WAITV(0);
        proc_ring(4); proc_ring(5); proc_ring(6); proc_ring(7);
        if (!ownw) wait_ge(&prog1[tid], t);
        __syncthreads();
        #pragma unroll
        for (int tt = 8; tt < 16; ++tt) issue_ring(tt);  // 32 loads
        WAITV(16);
        proc_ring(8); proc_ring(9); proc_ring(10); proc_ring(11);
        WAITV(0);
        proc_ring(12); proc_ring(13); proc_ring(14); proc_ring(15);
      } else {
        if (tid < 128)      wait_ge(&prog0[tid], t + 1);
        else if (tid < 256) wait_ge(&prog1[tid - 128], t);
        __syncthreads();
        #pragma unroll
        for (int tt = 0; tt < 8; ++tt) issue_ring(tt);
        WAITV(16);
        proc_ring(0); proc_ring(1); proc_ring(2); proc_ring(3);
        issue_ring(8); issue_ring(9); issue_ring(10); issue_ring(11);
        WAITV(16);
        proc_ring(4); proc_ring(5); proc_ring(6); proc_ring(7);
        issue_ring(12); issue_ring(13); issue_ring(14); issue_ring(15);
        WAITV(16);
        proc_ring(8); proc_ring(9); proc_ring(10); proc_ring(11);
        WAITV(0);
        proc_ring(12); proc_ring(13); proc_ring(14); proc_ring(15);
      }
    }

    float4v acc = accA + accB + accC;

    // ---- split-K reduction through LDS ----
    if (kh == 1) *(float4v*)(red + ((bg << 6) + lane) * 4) = acc;
    __syncthreads();
    if (kh == 0) {
      acc += *(const float4v*)(red + ((bg << 6) + lane) * 4);

      // activations: cols 0-11 sigmoid (i,f,o), 12-15 tanh (g)
      const bool isg = cc >= 12;
      float av[4];
      #pragma unroll
      for (int i = 0; i < 4; ++i) {
        float xg = acc[i];
        float arg = isg ? xg + xg : xg;
        float e = __expf(-fabsf(arg));
        float s = (arg >= 0.f) ? 1.f / (1.f + e) : e / (1.f + e);
        av[i] = isg ? (s + s - 1.f) : s;   // tanh(x) = 2*sigmoid(2x)-1
      }
      float hn[4];
      #pragma unroll
      for (int i = 0; i < 4; ++i) {
        float fv = __shfl_xor(av[i], 4);
        float ov = __shfl_xor(av[i], 8);
        float gv = __shfl_xor(av[i], 12);
        float cn = fv * cst[i] + av[i] * gv;
        cst[i] = cn;
        float e2 = __expf(-2.f * fabsf(cn));
        float th = (1.f - e2) / (1.f + e2);
        hn[i] = ov * ((cn >= 0.f) ? th : -th);
      }
      // in-wave transpose: lane (qq,cc<4) gathers row 4qq+cc, cols 4a+0..3
      float v0[4], v1[4], v2[4], v3[4];
      #pragma unroll
      for (int d = 0; d < 4; ++d) {
        int src = (lane & 0x30) | d;
        v0[d] = __shfl(hn[0], src);
        v1[d] = __shfl(hn[1], src);
        v2[d] = __shfl(hn[2], src);
        v3[d] = __shfl(hn[3], src);
      }
      if (cc < 4) {
        unsigned short hh[4], ll[4]; float4v hf;
        #pragma unroll
        for (int d = 0; d < 4; ++d) {
          float hv = (cc == 0) ? v0[d] : (cc == 1) ? v1[d] : (cc == 2) ? v2[d] : v3[d];
          hf[d] = hv;
          splitHL(hv, hh[d], ll[d]);
        }
        uint2v hi2, lo2;
        hi2[0] = (uint32_t)hh[0] | ((uint32_t)hh[1] << 16);
        hi2[1] = (uint32_t)hh[2] | ((uint32_t)hh[3] << 16);
        lo2[0] = (uint32_t)ll[0] | ((uint32_t)ll[1] << 16);
        lo2[1] = (uint32_t)ll[2] | ((uint32_t)ll[3] << 16);
        // full-line store: [jh=(a>>2)&1][lane'=16*(a&3)+4qq+cc] x 8B; the 16
        // active lanes cover one whole 128B line per plane (no RMW fill).
        uint8_t* dstb = (LAYER ? r1 : r0) + rbyte(slotC, bg, a >> 3)
                      + (size_t)((a >> 2) & 1) * 512
                      + (size_t)(16 * (a & 3) + 4 * qq + cc) * 8;
        asm volatile("global_store_dwordx2 %0, %1, off sc0 sc1\n\t"
                     "global_store_dwordx2 %0, %2, off offset:1024 sc0 sc1"
                     :: "v"(dstb), "v"(hi2), "v"(lo2) : "memory");
        if (LAYER && t == T_ - 1) {
          float4v* hp = (float4v*)(h1f + (size_t)(bg * 16 + 4 * qq + cc) * H_ + 4 * a);
          asm volatile("global_store_dwordx4 %0, %1, off sc0 sc1"
                       :: "v"(hp), "v"(hf) : "memory");
        }
      }
    }
    if constexpr (FULL) {
      // per-wave drain + flag (kh0), then end-of-step barrier: own-block
      // consumers are ordered by the barrier, so nobody polls own words.
      if (kh == 0) {
        asm volatile("s_waitcnt vmcnt(0)" ::: "memory");
        if (lane == 0)
          __hip_atomic_store(&myprog[bg * 128 + a], (uint32_t)(t + 1),
                             __ATOMIC_RELAXED, __HIP_MEMORY_SCOPE_AGENT);
      }
      __syncthreads();
    } else {
      asm volatile("s_waitcnt vmcnt(0)" ::: "memory");
      __syncthreads();
      if (tid == 0)
        __hip_atomic_store(&myprog[a], (uint32_t)(t + 1),
                           __ATOMIC_RELAXED, __HIP_MEMORY_SCOPE_AGENT);
    }
  }
}

template <bool FULL>
__global__ __launch_bounds__(NTHR_, 2) void lstm_persist(
    const float* __restrict__ x,
    const float* __restrict__ Wx0, const float* __restrict__ bx0, const float* __restrict__ Wh0,
    const float* __restrict__ Wx1, const float* __restrict__ bx1, const float* __restrict__ Wh1,
    uint32_t* prog0, uint32_t* prog1,
    uint8_t* ring0, uint8_t* ring1,
    float* h1f)
{
  __shared__ unsigned short Wsh[16384];  // 32 KB: W-hi frags
  __shared__ float red[1024];            // 4 KB: split-K reduction
  if (blockIdx.x < 128)
    run_layer<0, FULL>(blockIdx.x, x, Wx0, bx0, Wh0, prog0, prog1, ring0, ring1, h1f, Wsh, red);
  else
    run_layer<1, FULL>(blockIdx.x - 128, x, Wx1, bx1, Wh1, prog0, prog1, ring0, ring1, h1f, Wsh, red);
}

__global__ void fc_out(const float* __restrict__ h1f, const float* __restrict__ Wfc,
                       const float* __restrict__ bfc, float* __restrict__ out)
{
  int tid = threadIdx.x;
  int b = tid >> 3, p = tid & 7;
  const float* hp = h1f + (size_t)b * H_ + p * 64;
  const float* wp = Wfc + p * 64;
  float4v hv[16];
  #pragma unroll
  for (int q = 0; q < 16; ++q)
    asm volatile("global_load_dwordx4 %0, %1, off sc0 sc1"
                 : "=&v"(hv[q]) : "v"(hp + 4 * q) : "memory");
  asm volatile("s_waitcnt vmcnt(0)" ::: "memory");
  float s = 0.f;
  #pragma unroll
  for (int q = 0; q < 16; ++q) {
    float4v wv = *(const float4v*)(wp + 4 * q);
    s += hv[q][0] * wv[0] + hv[q][1] * wv[1] + hv[q][2] * wv[2] + hv[q][3] * wv[3];
  }
  s += __shfl_xor(s, 1);
  s += __shfl_xor(s, 2);
  s += __shfl_xor(s, 4);
  if (p == 0) out[b] = s + bfc[0];
}

extern "C" void kernel_launch(void* const* d_in, const int* in_sizes, int n_in,
                              void* d_out, int out_size, void* d_ws, size_t ws_size,
                              hipStream_t stream)
{
  const float* x   = (const float*)d_in[0];
  const float* Wx0 = (const float*)d_in[1];
  const float* bx0 = (const float*)d_in[2];
  const float* Wh0 = (const float*)d_in[3];
  const float* Wx1 = (const float*)d_in[4];
  const float* bx1 = (const float*)d_in[5];
  const float* Wh1 = (const float*)d_in[6];
  const float* Wfc = (const float*)d_in[7];
  const float* bfc = (const float*)d_in[8];

  uint8_t* ws = (uint8_t*)d_ws;
  const size_t RINGB_FULL = (size_t)(T_ + 1) * SLOT_B;   // 65.7 MB per ring
  const size_t RINGB_CYC  = (size_t)D_ * SLOT_B;         // 1 MB per ring
  const size_t NEED_FULL  = 4096 + 2 * RINGB_FULL + (size_t)B_ * H_ * 4;

  // flags: prog[layer][bg*128+a] -> 2 x 512 u32 = 4 KB
  uint32_t* prog0 = (uint32_t*)ws;
  uint32_t* prog1 = (uint32_t*)(ws + 2048);

  if (ws_size >= NEED_FULL) {
    uint8_t* ring0 = ws + 4096;
    uint8_t* ring1 = ws + 4096 + RINGB_FULL;
    float* h1f = (float*)(ws + 4096 + 2 * RINGB_FULL);
    (void)hipMemsetAsync(ws, 0, 4096 + SLOT_B, stream);   // flags + ring0 slot0
    (void)hipMemsetAsync(ring1, 0, SLOT_B, stream);       // ring1 slot0
    hipLaunchKernelGGL(lstm_persist<true>, dim3(256), dim3(NTHR_), 0, stream,
                       x, Wx0, bx0, Wh0, Wx1, bx1, Wh1,
                       prog0, prog1, ring0, ring1, h1f);
    hipLaunchKernelGGL(fc_out, dim3(1), dim3(512), 0, stream,
                       h1f, Wfc, bfc, (float*)d_out);
  } else {
    uint8_t* ring0 = ws + 4096;
    uint8_t* ring1 = ws + 4096 + RINGB_CYC;
    float* h1f = (float*)(ws + 4096 + 2 * RINGB_CYC);
    (void)hipMemsetAsync(ws, 0, 4096 + 2 * RINGB_CYC, stream);
    hipLaunchKernelGGL(lstm_persist<false>, dim3(256), dim3(NTHR_), 0, stream,
                       x, Wx0, bx0, Wh0, Wx1, bx1, Wh1,
                       prog0, prog1, ring0, ring1, h1f);
    hipLaunchKernelGGL(fc_out, dim3(1), dim3(512), 0, stream,
                       h1f, Wfc, bfc, (float*)d_out);
  }
}

// Round 14
// 3118.233 us; speedup vs baseline: 1.1132x; 1.1132x over previous
//
#include <hip/hip_runtime.h>
#include <stdint.h>

#define B_ 64
#define T_ 512
#define I_ 256
#define H_ 512
#define NTHR_ 512
#define D_ 8   // ring depth in CYC fallback mode

typedef __attribute__((ext_vector_type(8))) short short8;
typedef __attribute__((ext_vector_type(4))) float float4v;
typedef __attribute__((ext_vector_type(4))) unsigned int uint4v;

static_assert(sizeof(short8) == 16, "");

// tile = 2KB = [jh:2][lane':64][hi2 8B | lo2 8B].
// Writer block a fills plane jh=(a>>2)&1, lane' = 16*(a&3)+row, one dwordx4
// {hi2,lo2} per lane -> 16 lanes x 16B = 256B contiguous = 2 FULL 128B lines
// (no partial-line RMW). Reader lane l: dwordx4 at l*16 (jh0) and +1024 (jh1);
// h-frag = {jh0.hi, jh1.hi}, lo-frag = {jh0.lo, jh1.lo}. 2 loads/tile.
#define TILE_B 2048
#define SLOT_B ((size_t)4 * 16 * TILE_B)  // 128 KB per slot

// ---- bf16 helpers (round-to-nearest-even) ----
__device__ __forceinline__ unsigned short f2bf(float x) {
  union { float f; uint32_t u; } v; v.f = x;
  uint32_t r = v.u + 0x7FFFu + ((v.u >> 16) & 1u);
  return (unsigned short)(r >> 16);
}
__device__ __forceinline__ float bf2f(unsigned short h) {
  union { uint32_t u; float f; } v; v.u = ((uint32_t)h) << 16; return v.f;
}
__device__ __forceinline__ void splitHL(float x, unsigned short& hi, unsigned short& lo) {
  hi = f2bf(x);
  lo = f2bf(x - bf2f(hi));   // x - hi is exact in fp32
}

// byte offset of a (slot,bg,ktile) tile
__device__ __forceinline__ size_t rbyte(int slot, int bg, int ht) {
  return ((size_t)slot * 64 + bg * 16 + ht) * TILE_B;
}

// per-thread spin on one progress word (bypass load)
__device__ __forceinline__ void wait_ge(const uint32_t* p, int tgt) {
  if (tgt <= 0) return;
  int it = 0;
  while ((int)__hip_atomic_load(p, __ATOMIC_RELAXED, __HIP_MEMORY_SCOPE_AGENT) < tgt) {
    __builtin_amdgcn_s_sleep(1);
    if (++it > 2000000) break;   // safety: degrade to wrong answer, never hang
  }
}

__device__ __forceinline__ short8 mk8(uint32_t a0, uint32_t a1, uint32_t b0, uint32_t b1) {
  union { uint32_t u[4]; short8 s; } t;
  t.u[0] = a0; t.u[1] = a1; t.u[2] = b0; t.u[3] = b1;
  return t.s;
}

#define MFMA16(A, Bv, C) __builtin_amdgcn_mfma_f32_16x16x32_bf16(A, Bv, C, 0, 0, 0)

// counted wait on our asm-issued vmem + scheduling fence (rule #18)
#define WAITV(n) do { \
    asm volatile("s_waitcnt vmcnt(" #n ")" ::: "memory"); \
    __builtin_amdgcn_sched_barrier(0); \
  } while (0)

// One LSTM layer, persistent. 8 waves/block: (bg 0..3) x (kh 0..1), split-K.
// Block 'a' owns h-cols [4a,4a+4) -> 16 gate cols. K: [0,K1)=inp, [K1,K1+512)=h.
// MFMA frags: k(q,j)=4q+(j&3)+16*(j>>2); A-row=lane&15, B-col=lane&15,
// C/D col=lane&15 row=4*(lane>>4)+i (m89-verified).
// Round-14: interleaved hi|lo tile layout -> full-line writes (1 store/lane)
// AND dwordx4 reads (2 loads/tile). Explicit safe vmcnt counts.
// Everything else = round-12 structure.
template <int LAYER, bool FULL>
__device__ void run_layer(
    int a,
    const float* __restrict__ x,
    const float* __restrict__ Wxp, const float* __restrict__ bxp,
    const float* __restrict__ Whp,
    uint32_t* prog0, uint32_t* prog1,
    uint8_t* r0, uint8_t* r1,
    float* h1f,
    unsigned short* Wsh, float* red)
{
  constexpr int K1 = LAYER ? H_ : I_;
  constexpr int NT = (K1 + H_) / 32;   // 24 (L0) or 32 (L1) K-tiles
  constexpr int NTT = NT / 2;          // 12 or 16 tiles per k-half wavegroup
  const int tid = threadIdx.x;
  const int lane = tid & 63;
  const int wid = tid >> 6;     // 0..7
  const int bg = wid & 3;       // batch group (16 batches)
  const int kh = wid >> 2;      // K-half (tile parity)
  const int qq = lane >> 4;
  const int cc = lane & 15;
  const int brow = bg * 16 + cc;

  // ---- stage weight slice: pass0 = LO (pulled to regs), pass1 = HI (stays in LDS) ----
  short8 wlo[NTT];
  for (int pass = 0; pass < 2; ++pass) {
    for (int idx = tid; idx < NT * 512; idx += NTHR_) {
      int tile = idx >> 9, r = idx & 511, ln = r >> 3, j = r & 7;
      int k = tile * 32 + 4 * (ln >> 4) + (j & 3) + 16 * (j >> 2);
      int n = 4 * a + (ln & 3);
      int g = (ln & 15) >> 2;
      float wvv = (k < K1) ? Wxp[((size_t)g * K1 + k) * H_ + n]
                           : Whp[((size_t)g * H_ + (k - K1)) * H_ + n];
      unsigned short hi, lo; splitHL(wvv, hi, lo);
      Wsh[idx] = pass ? hi : lo;
    }
    __syncthreads();
    if (pass == 0) {
      #pragma unroll
      for (int tt = 0; tt < NTT; ++tt) {
        int tile = 2 * tt + kh;
        wlo[tt] = *(const short8*)(Wsh + tile * 512 + lane * 8);
      }
      __syncthreads();   // all pulled before HI overwrites
    }
  }

  const float biasv = bxp[(size_t)(cc >> 2) * H_ + 4 * a + (cc & 3)];
  float cst[4] = {0.f, 0.f, 0.f, 0.f};

  uint32_t* myprog = LAYER ? prog1 : prog0;
  const bool ownw = FULL ? ((tid & 127) == a) : false;

  for (int t = 0; t < T_; ++t) {
    const int slotP = FULL ? t       : (t & (D_ - 1));        // h[t-1]
    const int slotC = FULL ? (t + 1) : ((t + 1) & (D_ - 1));  // h[t]
    const float bv = (kh == 0) ? biasv : 0.f;   // bias only in kh0 (split-K sums halves)
    float4v accA = {bv, bv, bv, bv};              // hi*Whi (+bias in kh0)
    float4v accB = {0.f, 0.f, 0.f, 0.f};          // lo*Whi
    float4v accC = {0.f, 0.f, 0.f, 0.f};          // hi*Wlo

    uint4v X0[8], X1[8];   // per-tile jh0/jh1 {hi2,lo2} chunks

    auto issue_ring = [&](int tt) {
      const int tile = 2 * tt + kh;
      const uint8_t* p;
      if (!LAYER)         p = r0 + rbyte(slotP, bg, tile - 8);
      else if (tile < 16) p = r0 + rbyte(slotC, bg, tile);
      else                p = r1 + rbyte(slotP, bg, tile - 16);
      p += (size_t)lane * 16;
      const int s = tt & 7;
      if constexpr (FULL) {
        asm volatile("global_load_dwordx4 %0, %2, off\n\t"
                     "global_load_dwordx4 %1, %2, off offset:1024"
                     : "=&v"(X0[s]), "=&v"(X1[s]) : "v"(p) : "memory");
      } else {
        asm volatile("global_load_dwordx4 %0, %2, off sc0 sc1\n\t"
                     "global_load_dwordx4 %1, %2, off offset:1024 sc0 sc1"
                     : "=&v"(X0[s]), "=&v"(X1[s]) : "v"(p) : "memory");
      }
    };
    auto proc_ring = [&](int tt) {
      const int tile = 2 * tt + kh;
      const int s = tt & 7;
      short8 h = mk8(X0[s][0], X0[s][1], X1[s][0], X1[s][1]);
      short8 l = mk8(X0[s][2], X0[s][3], X1[s][2], X1[s][3]);
      short8 bhi = *(const short8*)(Wsh + tile * 512 + lane * 8);
      accA = MFMA16(h, bhi, accA);
      accB = MFMA16(l, bhi, accB);
      accC = MFMA16(h, wlo[tt], accC);
    };

    if constexpr (!LAYER) {
      uint4v xw0[4], xw1[4];
      #pragma unroll
      for (int u = 0; u < 4; ++u) {        // x tiles 2u+kh (read-only: cached)
        const float* xp = x + ((size_t)brow * T_ + t) * I_ + (2 * u + kh) * 32 + 4 * qq;
        asm volatile("global_load_dwordx4 %0, %2, off\n\t"
                     "global_load_dwordx4 %1, %2, off offset:64"
                     : "=&v"(xw0[u]), "=&v"(xw1[u]) : "v"(xp) : "memory");
      }
      if constexpr (FULL) {
        if (!ownw) wait_ge(&prog0[tid], t);
      } else {
        if (tid < 128)      wait_ge(&prog0[tid], t);
        else if (tid < 256) wait_ge(&prog1[tid - 128], t - (D_ - 1));
      }
      __syncthreads();
      #pragma unroll
      for (int tt = 4; tt < 12; ++tt) issue_ring(tt);   // 16 loads
      WAITV(16);                           // x-guard: all pre-ring loads landed
      #pragma unroll
      for (int u = 0; u < 4; ++u) {        // convert+MFMA x under ring flight
        short8 ahi, alo;
        #pragma unroll
        for (int j = 0; j < 4; ++j) {
          unsigned short hh, ll;
          splitHL(__uint_as_float(xw0[u][j]), hh, ll); ahi[j] = (short)hh; alo[j] = (short)ll;
          splitHL(__uint_as_float(xw1[u][j]), hh, ll); ahi[j + 4] = (short)hh; alo[j + 4] = (short)ll;
        }
        const int tile = 2 * u + kh;
        short8 bhi = *(const short8*)(Wsh + tile * 512 + lane * 8);
        accA = MFMA16(ahi, bhi, accA);
        accB = MFMA16(alo, bhi, accB);
        accC = MFMA16(ahi, wlo[u], accC);
      }
      WAITV(8);                            // tiles 4..7 landed
      proc_ring(4); proc_ring(5); proc_ring(6); proc_ring(7);
      WAITV(0);
      proc_ring(8); proc_ring(9); proc_ring(10); proc_ring(11);
    } else {
      if constexpr (FULL) {
        // split poll: h0 half first (L0 ahead -> ~instant), then own-layer wait
        wait_ge(&prog0[tid], t + 1);
        __syncthreads();
        #pragma unroll
        for (int tt = 0; tt < 8; ++tt) issue_ring(tt);   // 16 loads
        WAITV(8);
        proc_ring(0); proc_ring(1); proc_ring(2); proc_ring(3);
        WAITV(0);
        proc_ring(4); proc_ring(5); proc_ring(6); proc_ring(7);
        if (!ownw) wait_ge(&prog1[tid], t);
        __syncthreads();
        #pragma unroll
        for (int tt = 8; tt < 16; ++tt) issue_ring(tt);  // 16 loads
        WAITV(8);
        proc_ring(8); proc_ring(9); proc_ring(10); proc_ring(11);
        WAITV(0);
        proc_ring(12); proc_ring(13); proc_ring(14); proc_ring(15);
      } else {
        if (tid < 128)      wait_ge(&prog0[tid], t + 1);
        else if (tid < 256) wait_ge(&prog1[tid - 128], t);
        __syncthreads();
        #pragma unroll
        for (int tt = 0; tt < 8; ++tt) issue_ring(tt);   // 16 loads
        WAITV(8);
        proc_ring(0); proc_ring(1); proc_ring(2); proc_ring(3);
        issue_ring(8); issue_ring(9); issue_ring(10); issue_ring(11);
        WAITV(8);                          // tiles 4..7 landed
        proc_ring(4); proc_ring(5); proc_ring(6); proc_ring(7);
        issue_ring(12); issue_ring(13); issue_ring(14); issue_ring(15);
        WAITV(8);                          // tiles 8..11 landed
        proc_ring(8); proc_ring(9); proc_ring(10); proc_ring(11);
        WAITV(0);
        proc_ring(12); proc_ring(13); proc_ring(14); proc_ring(15);
      }
    }

    float4v acc = accA + accB + accC;

    // ---- split-K reduction through LDS ----
    if (kh == 1) *(float4v*)(red + ((bg << 6) + lane) * 4) = acc;
    __syncthreads();
    if (kh == 0) {
      acc += *(const float4v*)(red + ((bg << 6) + lane) * 4);

      // activations: cols 0-11 sigmoid (i,f,o), 12-15 tanh (g)
      const bool isg = cc >= 12;
      float av[4];
      #pragma unroll
      for (int i = 0; i < 4; ++i) {
        float xg = acc[i];
        float arg = isg ? xg + xg : xg;
        float e = __expf(-fabsf(arg));
        float s = (arg >= 0.f) ? 1.f / (1.f + e) : e / (1.f + e);
        av[i] = isg ? (s + s - 1.f) : s;   // tanh(x) = 2*sigmoid(2x)-1
      }
      float hn[4];
      #pragma unroll
      for (int i = 0; i < 4; ++i) {
        float fv = __shfl_xor(av[i], 4);
        float ov = __shfl_xor(av[i], 8);
        float gv = __shfl_xor(av[i], 12);
        float cn = fv * cst[i] + av[i] * gv;
        cst[i] = cn;
        float e2 = __expf(-2.f * fabsf(cn));
        float th = (1.f - e2) / (1.f + e2);
        hn[i] = ov * ((cn >= 0.f) ? th : -th);
      }
      // in-wave transpose: lane (qq,cc<4) gathers row 4qq+cc, cols 4a+0..3
      float v0[4], v1[4], v2[4], v3[4];
      #pragma unroll
      for (int d = 0; d < 4; ++d) {
        int src = (lane & 0x30) | d;
        v0[d] = __shfl(hn[0], src);
        v1[d] = __shfl(hn[1], src);
        v2[d] = __shfl(hn[2], src);
        v3[d] = __shfl(hn[3], src);
      }
      if (cc < 4) {
        unsigned short hh[4], ll[4]; float4v hf;
        #pragma unroll
        for (int d = 0; d < 4; ++d) {
          float hv = (cc == 0) ? v0[d] : (cc == 1) ? v1[d] : (cc == 2) ? v2[d] : v3[d];
          hf[d] = hv;
          splitHL(hv, hh[d], ll[d]);
        }
        uint4v pk;
        pk[0] = (uint32_t)hh[0] | ((uint32_t)hh[1] << 16);
        pk[1] = (uint32_t)hh[2] | ((uint32_t)hh[3] << 16);
        pk[2] = (uint32_t)ll[0] | ((uint32_t)ll[1] << 16);
        pk[3] = (uint32_t)ll[2] | ((uint32_t)ll[3] << 16);
        // one dwordx4 per lane; 16 lanes -> 256B contiguous = 2 full lines
        uint8_t* dstb = (LAYER ? r1 : r0) + rbyte(slotC, bg, a >> 3)
                      + (size_t)((a >> 2) & 1) * 1024
                      + (size_t)(16 * (a & 3) + 4 * qq + cc) * 16;
        asm volatile("global_store_dwordx4 %0, %1, off sc0 sc1"
                     :: "v"(dstb), "v"(pk) : "memory");
        if (LAYER && t == T_ - 1) {
          float4v* hp = (float4v*)(h1f + (size_t)(bg * 16 + 4 * qq + cc) * H_ + 4 * a);
          asm volatile("global_store_dwordx4 %0, %1, off sc0 sc1"
                       :: "v"(hp), "v"(hf) : "memory");
        }
      }
    }
    if constexpr (FULL) {
      // per-wave drain + flag (kh0), then end-of-step barrier: own-block
      // consumers are ordered by the barrier, so nobody polls own words.
      if (kh == 0) {
        asm volatile("s_waitcnt vmcnt(0)" ::: "memory");
        if (lane == 0)
          __hip_atomic_store(&myprog[bg * 128 + a], (uint32_t)(t + 1),
                             __ATOMIC_RELAXED, __HIP_MEMORY_SCOPE_AGENT);
      }
      __syncthreads();
    } else {
      asm volatile("s_waitcnt vmcnt(0)" ::: "memory");
      __syncthreads();
      if (tid == 0)
        __hip_atomic_store(&myprog[a], (uint32_t)(t + 1),
                           __ATOMIC_RELAXED, __HIP_MEMORY_SCOPE_AGENT);
    }
  }
}

template <bool FULL>
__global__ __launch_bounds__(NTHR_, 2) void lstm_persist(
    const float* __restrict__ x,
    const float* __restrict__ Wx0, const float* __restrict__ bx0, const float* __restrict__ Wh0,
    const float* __restrict__ Wx1, const float* __restrict__ bx1, const float* __restrict__ Wh1,
    uint32_t* prog0, uint32_t* prog1,
    uint8_t* ring0, uint8_t* ring1,
    float* h1f)
{
  __shared__ unsigned short Wsh[16384];  // 32 KB: W-hi frags
  __shared__ float red[1024];            // 4 KB: split-K reduction
  if (blockIdx.x < 128)
    run_layer<0, FULL>(blockIdx.x, x, Wx0, bx0, Wh0, prog0, prog1, ring0, ring1, h1f, Wsh, red);
  else
    run_layer<1, FULL>(blockIdx.x - 128, x, Wx1, bx1, Wh1, prog0, prog1, ring0, ring1, h1f, Wsh, red);
}

__global__ void fc_out(const float* __restrict__ h1f, const float* __restrict__ Wfc,
                       const float* __restrict__ bfc, float* __restrict__ out)
{
  int tid = threadIdx.x;
  int b = tid >> 3, p = tid & 7;
  const float* hp = h1f + (size_t)b * H_ + p * 64;
  const float* wp = Wfc + p * 64;
  float4v hv[16];
  #pragma unroll
  for (int q = 0; q < 16; ++q)
    asm volatile("global_load_dwordx4 %0, %1, off sc0 sc1"
                 : "=&v"(hv[q]) : "v"(hp + 4 * q) : "memory");
  asm volatile("s_waitcnt vmcnt(0)" ::: "memory");
  float s = 0.f;
  #pragma unroll
  for (int q = 0; q < 16; ++q) {
    float4v wv = *(const float4v*)(wp + 4 * q);
    s += hv[q][0] * wv[0] + hv[q][1] * wv[1] + hv[q][2] * wv[2] + hv[q][3] * wv[3];
  }
  s += __shfl_xor(s, 1);
  s += __shfl_xor(s, 2);
  s += __shfl_xor(s, 4);
  if (p == 0) out[b] = s + bfc[0];
}

extern "C" void kernel_launch(void* const* d_in, const int* in_sizes, int n_in,
                              void* d_out, int out_size, void* d_ws, size_t ws_size,
                              hipStream_t stream)
{
  const float* x   = (const float*)d_in[0];
  const float* Wx0 = (const float*)d_in[1];
  const float* bx0 = (const float*)d_in[2];
  const float* Wh0 = (const float*)d_in[3];
  const float* Wx1 = (const float*)d_in[4];
  const float* bx1 = (const float*)d_in[5];
  const float* Wh1 = (const float*)d_in[6];
  const float* Wfc = (const float*)d_in[7];
  const float* bfc = (const float*)d_in[8];

  uint8_t* ws = (uint8_t*)d_ws;
  const size_t RINGB_FULL = (size_t)(T_ + 1) * SLOT_B;   // 65.7 MB per ring
  const size_t RINGB_CYC  = (size_t)D_ * SLOT_B;         // 1 MB per ring
  const size_t NEED_FULL  = 4096 + 2 * RINGB_FULL + (size_t)B_ * H_ * 4;

  // flags: prog[layer][bg*128+a] -> 2 x 512 u32 = 4 KB
  uint32_t* prog0 = (uint32_t*)ws;
  uint32_t* prog1 = (uint32_t*)(ws + 2048);

  if (ws_size >= NEED_FULL) {
    uint8_t* ring0 = ws + 4096;
    uint8_t* ring1 = ws + 4096 + RINGB_FULL;
    float* h1f = (float*)(ws + 4096 + 2 * RINGB_FULL);
    (void)hipMemsetAsync(ws, 0, 4096 + SLOT_B, stream);   // flags + ring0 slot0
    (void)hipMemsetAsync(ring1, 0, SLOT_B, stream);       // ring1 slot0
    hipLaunchKernelGGL(lstm_persist<true>, dim3(256), dim3(NTHR_), 0, stream,
                       x, Wx0, bx0, Wh0, Wx1, bx1, Wh1,
                       prog0, prog1, ring0, ring1, h1f);
    hipLaunchKernelGGL(fc_out, dim3(1), dim3(512), 0, stream,
                       h1f, Wfc, bfc, (float*)d_out);
  } else {
    uint8_t* ring0 = ws + 4096;
    uint8_t* ring1 = ws + 4096 + RINGB_CYC;
    float* h1f = (float*)(ws + 4096 + 2 * RINGB_CYC);
    (void)hipMemsetAsync(ws, 0, 4096 + 2 * RINGB_CYC, stream);
    hipLaunchKernelGGL(lstm_persist<false>, dim3(256), dim3(NTHR_), 0, stream,
                       x, Wx0, bx0, Wh0, Wx1, bx1, Wh1,
                       prog0, prog1, ring0, ring1, h1f);
    hipLaunchKernelGGL(fc_out, dim3(1), dim3(512), 0, stream,
                       h1f, Wfc, bfc, (float*)d_out);
  }
}

// Round 15
// 2748.768 us; speedup vs baseline: 1.2629x; 1.1344x over previous
//
#include <hip/hip_runtime.h>
#include <stdint.h>

#define B_ 64
#define T_ 512
#define I_ 256
#define H_ 512
#define NTHR_ 512
#define D_ 8   // ring depth in CYC fallback mode

typedef __attribute__((ext_vector_type(8))) short short8;
typedef __attribute__((ext_vector_type(4))) float float4v;
typedef __attribute__((ext_vector_type(4))) unsigned int uint4v;

static_assert(sizeof(short8) == 16, "");

// tile = 2KB = [jh:2][lane':64][hi2 8B | lo2 8B].
// Writer block a fills plane jh=(a>>2)&1, lane' = 16*(a&3)+row, one dwordx4
// {hi2,lo2} per lane -> 256B contiguous = 2 FULL 128B lines (no RMW).
// Reader lane l: dwordx4 at l*16 (jh0) and +1024 (jh1). 2 loads/tile.
#define TILE_B 2048
#define SLOT_B ((size_t)4 * 16 * TILE_B)  // 128 KB per slot

// ---- bf16 helpers (round-to-nearest-even) ----
__device__ __forceinline__ unsigned short f2bf(float x) {
  union { float f; uint32_t u; } v; v.f = x;
  uint32_t r = v.u + 0x7FFFu + ((v.u >> 16) & 1u);
  return (unsigned short)(r >> 16);
}
__device__ __forceinline__ float bf2f(unsigned short h) {
  union { uint32_t u; float f; } v; v.u = ((uint32_t)h) << 16; return v.f;
}
__device__ __forceinline__ void splitHL(float x, unsigned short& hi, unsigned short& lo) {
  hi = f2bf(x);
  lo = f2bf(x - bf2f(hi));   // x - hi is exact in fp32
}

// byte offset of a (slot,bg,ktile) tile
__device__ __forceinline__ size_t rbyte(int slot, int bg, int ht) {
  return ((size_t)slot * 64 + bg * 16 + ht) * TILE_B;
}

// per-thread spin on one progress word (bypass load); hot-spin 32 iters
// before sleeping for low detect latency on short waits
__device__ __forceinline__ void wait_ge(const uint32_t* p, int tgt) {
  if (tgt <= 0) return;
  int it = 0;
  while ((int)__hip_atomic_load(p, __ATOMIC_RELAXED, __HIP_MEMORY_SCOPE_AGENT) < tgt) {
    if (++it > 2000000) break;   // safety: degrade to wrong answer, never hang
    if (it > 32) __builtin_amdgcn_s_sleep(1);
  }
}

__device__ __forceinline__ short8 mk8(uint32_t a0, uint32_t a1, uint32_t b0, uint32_t b1) {
  union { uint32_t u[4]; short8 s; } t;
  t.u[0] = a0; t.u[1] = a1; t.u[2] = b0; t.u[3] = b1;
  return t.s;
}

#define MFMA16(A, Bv, C) __builtin_amdgcn_mfma_f32_16x16x32_bf16(A, Bv, C, 0, 0, 0)

// counted wait on our asm-issued vmem + scheduling fence (rule #18)
#define WAITV(n) do { \
    asm volatile("s_waitcnt vmcnt(" #n ")" ::: "memory"); \
    __builtin_amdgcn_sched_barrier(0); \
  } while (0)

// One LSTM layer, persistent. 8 waves/block: (bg 0..3) x (kh 0..1), split-K.
// Block 'a' owns h-cols [4a,4a+4) -> 16 gate cols. K: [0,K1)=inp, [K1,K1+512)=h.
// MFMA frags: k(q,j)=4q+(j&3)+16*(j>>2); A-row=lane&15, B-col=lane&15,
// C/D col=lane&15 row=4*(lane>>4)+i (m89-verified).
// Round-15 changes: (1) L1 issues ring0 BEFORE poll1 (fetch hides under the
// wait; poll's own load drains vmcnt) and interleaves ring1 issue with ring0
// proc; (2) optional XPK: x pre-converted to ring-tile layout by prep kernel
// -> L0 x path = plain tile loads, zero splitHL VALU; (3) hot-spin poll.
template <int LAYER, bool FULL, bool XPK>
__device__ void run_layer(
    int a,
    const float* __restrict__ x,
    const uint8_t* __restrict__ xpk,
    const float* __restrict__ Wxp, const float* __restrict__ bxp,
    const float* __restrict__ Whp,
    uint32_t* prog0, uint32_t* prog1,
    uint8_t* r0, uint8_t* r1,
    float* h1f,
    unsigned short* Wsh, float* red)
{
  constexpr int K1 = LAYER ? H_ : I_;
  constexpr int NT = (K1 + H_) / 32;   // 24 (L0) or 32 (L1) K-tiles
  constexpr int NTT = NT / 2;          // 12 or 16 tiles per k-half wavegroup
  const int tid = threadIdx.x;
  const int lane = tid & 63;
  const int wid = tid >> 6;     // 0..7
  const int bg = wid & 3;       // batch group (16 batches)
  const int kh = wid >> 2;      // K-half (tile parity)
  const int qq = lane >> 4;
  const int cc = lane & 15;
  const int brow = bg * 16 + cc;

  // ---- stage weight slice: pass0 = LO (pulled to regs), pass1 = HI (stays in LDS) ----
  short8 wlo[NTT];
  for (int pass = 0; pass < 2; ++pass) {
    for (int idx = tid; idx < NT * 512; idx += NTHR_) {
      int tile = idx >> 9, r = idx & 511, ln = r >> 3, j = r & 7;
      int k = tile * 32 + 4 * (ln >> 4) + (j & 3) + 16 * (j >> 2);
      int n = 4 * a + (ln & 3);
      int g = (ln & 15) >> 2;
      float wvv = (k < K1) ? Wxp[((size_t)g * K1 + k) * H_ + n]
                           : Whp[((size_t)g * H_ + (k - K1)) * H_ + n];
      unsigned short hi, lo; splitHL(wvv, hi, lo);
      Wsh[idx] = pass ? hi : lo;
    }
    __syncthreads();
    if (pass == 0) {
      #pragma unroll
      for (int tt = 0; tt < NTT; ++tt) {
        int tile = 2 * tt + kh;
        wlo[tt] = *(const short8*)(Wsh + tile * 512 + lane * 8);
      }
      __syncthreads();   // all pulled before HI overwrites
    }
  }

  const float biasv = bxp[(size_t)(cc >> 2) * H_ + 4 * a + (cc & 3)];
  float cst[4] = {0.f, 0.f, 0.f, 0.f};

  uint32_t* myprog = LAYER ? prog1 : prog0;
  const bool ownw = FULL ? ((tid & 127) == a) : false;

  for (int t = 0; t < T_; ++t) {
    const int slotP = FULL ? t       : (t & (D_ - 1));        // h[t-1]
    const int slotC = FULL ? (t + 1) : ((t + 1) & (D_ - 1));  // h[t]
    const float bv = (kh == 0) ? biasv : 0.f;   // bias only in kh0 (split-K sums halves)
    float4v accA = {bv, bv, bv, bv};              // hi*Whi (+bias in kh0)
    float4v accB = {0.f, 0.f, 0.f, 0.f};          // lo*Whi
    float4v accC = {0.f, 0.f, 0.f, 0.f};          // hi*Wlo

    uint4v X0[8], X1[8];   // per-tile jh0/jh1 {hi2,lo2} chunks

    auto issue_ring = [&](int tt) {
      const int tile = 2 * tt + kh;
      const uint8_t* p;
      if (!LAYER)         p = r0 + rbyte(slotP, bg, tile - 8);
      else if (tile < 16) p = r0 + rbyte(slotC, bg, tile);
      else                p = r1 + rbyte(slotP, bg, tile - 16);
      p += (size_t)lane * 16;
      const int s = tt & 7;
      if constexpr (FULL) {
        asm volatile("global_load_dwordx4 %0, %2, off\n\t"
                     "global_load_dwordx4 %1, %2, off offset:1024"
                     : "=&v"(X0[s]), "=&v"(X1[s]) : "v"(p) : "memory");
      } else {
        asm volatile("global_load_dwordx4 %0, %2, off sc0 sc1\n\t"
                     "global_load_dwordx4 %1, %2, off offset:1024 sc0 sc1"
                     : "=&v"(X0[s]), "=&v"(X1[s]) : "v"(p) : "memory");
      }
    };
    auto issue_x = [&](int tt) {   // XPK: x tile in ring layout, cached
      const int tile = 2 * tt + kh;
      const uint8_t* p = xpk + (((size_t)t * 4 + bg) * 8 + tile) * TILE_B
                       + (size_t)lane * 16;
      const int s = tt & 7;
      asm volatile("global_load_dwordx4 %0, %2, off\n\t"
                   "global_load_dwordx4 %1, %2, off offset:1024"
                   : "=&v"(X0[s]), "=&v"(X1[s]) : "v"(p) : "memory");
    };
    auto proc_ring = [&](int tt) {
      const int tile = 2 * tt + kh;
      const int s = tt & 7;
      short8 h = mk8(X0[s][0], X0[s][1], X1[s][0], X1[s][1]);
      short8 l = mk8(X0[s][2], X0[s][3], X1[s][2], X1[s][3]);
      short8 bhi = *(const short8*)(Wsh + tile * 512 + lane * 8);
      accA = MFMA16(h, bhi, accA);
      accB = MFMA16(l, bhi, accB);
      accC = MFMA16(h, wlo[tt], accC);
    };

    if constexpr (!LAYER) {
      if constexpr (XPK) {
        #pragma unroll
        for (int tt = 0; tt < 4; ++tt) issue_x(tt);       // 8 loads, s0..3
        if constexpr (FULL) {
          if (!ownw) wait_ge(&prog0[tid], t);             // drains x under poll
        }
        __syncthreads();
        #pragma unroll
        for (int tt = 4; tt < 8; ++tt) issue_ring(tt);    // 8 loads, s4..7
        WAITV(8);                                          // x tiles landed
        proc_ring(0); proc_ring(1); proc_ring(2); proc_ring(3);
        issue_ring(8); issue_ring(9); issue_ring(10); issue_ring(11);  // s0..3
        WAITV(8);                                          // tiles 4..7 landed
        proc_ring(4); proc_ring(5); proc_ring(6); proc_ring(7);
        WAITV(0);
        proc_ring(8); proc_ring(9); proc_ring(10); proc_ring(11);
      } else {
        uint4v xw0[4], xw1[4];
        #pragma unroll
        for (int u = 0; u < 4; ++u) {        // x tiles 2u+kh (read-only: cached)
          const float* xp = x + ((size_t)brow * T_ + t) * I_ + (2 * u + kh) * 32 + 4 * qq;
          asm volatile("global_load_dwordx4 %0, %2, off\n\t"
                       "global_load_dwordx4 %1, %2, off offset:64"
                       : "=&v"(xw0[u]), "=&v"(xw1[u]) : "v"(xp) : "memory");
        }
        if constexpr (FULL) {
          if (!ownw) wait_ge(&prog0[tid], t);
        } else {
          if (tid < 128)      wait_ge(&prog0[tid], t);
          else if (tid < 256) wait_ge(&prog1[tid - 128], t - (D_ - 1));
        }
        __syncthreads();
        #pragma unroll
        for (int tt = 4; tt < 12; ++tt) issue_ring(tt);   // 16 loads
        WAITV(16);                           // x-guard: all pre-ring loads landed
        #pragma unroll
        for (int u = 0; u < 4; ++u) {        // convert+MFMA x under ring flight
          short8 ahi, alo;
          #pragma unroll
          for (int j = 0; j < 4; ++j) {
            unsigned short hh, ll;
            splitHL(__uint_as_float(xw0[u][j]), hh, ll); ahi[j] = (short)hh; alo[j] = (short)ll;
            splitHL(__uint_as_float(xw1[u][j]), hh, ll); ahi[j + 4] = (short)hh; alo[j + 4] = (short)ll;
          }
          const int tile = 2 * u + kh;
          short8 bhi = *(const short8*)(Wsh + tile * 512 + lane * 8);
          accA = MFMA16(ahi, bhi, accA);
          accB = MFMA16(alo, bhi, accB);
          accC = MFMA16(ahi, wlo[u], accC);
        }
        WAITV(8);                            // tiles 4..7 landed
        proc_ring(4); proc_ring(5); proc_ring(6); proc_ring(7);
        WAITV(0);
        proc_ring(8); proc_ring(9); proc_ring(10); proc_ring(11);
      }
    } else {
      if constexpr (FULL) {
        // ring0 issued BEFORE the real wait: fetch hides under poll1 (the
        // poll's own load drains vmcnt). Then ring1 issue interleaves with
        // ring0 proc so its fetch hides under MFMAs.
        wait_ge(&prog0[tid], t + 1);         // h0[t]: L0 ahead -> ~instant
        __syncthreads();
        #pragma unroll
        for (int tt = 0; tt < 8; ++tt) issue_ring(tt);   // ring0: 16 loads
        if (!ownw) wait_ge(&prog1[tid], t);  // the real wait; ring0 lands here
        __syncthreads();
        WAITV(8);
        proc_ring(0); proc_ring(1); proc_ring(2); proc_ring(3);
        issue_ring(8); issue_ring(9); issue_ring(10); issue_ring(11);   // s0..3
        WAITV(8);
        proc_ring(4); proc_ring(5); proc_ring(6); proc_ring(7);
        issue_ring(12); issue_ring(13); issue_ring(14); issue_ring(15); // s4..7
        WAITV(8);
        proc_ring(8); proc_ring(9); proc_ring(10); proc_ring(11);
        WAITV(0);
        proc_ring(12); proc_ring(13); proc_ring(14); proc_ring(15);
      } else {
        if (tid < 128)      wait_ge(&prog0[tid], t + 1);
        else if (tid < 256) wait_ge(&prog1[tid - 128], t);
        __syncthreads();
        #pragma unroll
        for (int tt = 0; tt < 8; ++tt) issue_ring(tt);   // 16 loads
        WAITV(8);
        proc_ring(0); proc_ring(1); proc_ring(2); proc_ring(3);
        issue_ring(8); issue_ring(9); issue_ring(10); issue_ring(11);
        WAITV(8);                          // tiles 4..7 landed
        proc_ring(4); proc_ring(5); proc_ring(6); proc_ring(7);
        issue_ring(12); issue_ring(13); issue_ring(14); issue_ring(15);
        WAITV(8);                          // tiles 8..11 landed
        proc_ring(8); proc_ring(9); proc_ring(10); proc_ring(11);
        WAITV(0);
        proc_ring(12); proc_ring(13); proc_ring(14); proc_ring(15);
      }
    }

    float4v acc = accA + accB + accC;

    // ---- split-K reduction through LDS ----
    if (kh == 1) *(float4v*)(red + ((bg << 6) + lane) * 4) = acc;
    __syncthreads();
    if (kh == 0) {
      acc += *(const float4v*)(red + ((bg << 6) + lane) * 4);

      // activations: cols 0-11 sigmoid (i,f,o), 12-15 tanh (g)
      const bool isg = cc >= 12;
      float av[4];
      #pragma unroll
      for (int i = 0; i < 4; ++i) {
        float xg = acc[i];
        float arg = isg ? xg + xg : xg;
        float e = __expf(-fabsf(arg));
        float s = (arg >= 0.f) ? 1.f / (1.f + e) : e / (1.f + e);
        av[i] = isg ? (s + s - 1.f) : s;   // tanh(x) = 2*sigmoid(2x)-1
      }
      float hn[4];
      #pragma unroll
      for (int i = 0; i < 4; ++i) {
        float fv = __shfl_xor(av[i], 4);
        float ov = __shfl_xor(av[i], 8);
        float gv = __shfl_xor(av[i], 12);
        float cn = fv * cst[i] + av[i] * gv;
        cst[i] = cn;
        float e2 = __expf(-2.f * fabsf(cn));
        float th = (1.f - e2) / (1.f + e2);
        hn[i] = ov * ((cn >= 0.f) ? th : -th);
      }
      // in-wave transpose: lane (qq,cc<4) gathers row 4qq+cc, cols 4a+0..3
      float v0[4], v1[4], v2[4], v3[4];
      #pragma unroll
      for (int d = 0; d < 4; ++d) {
        int src = (lane & 0x30) | d;
        v0[d] = __shfl(hn[0], src);
        v1[d] = __shfl(hn[1], src);
        v2[d] = __shfl(hn[2], src);
        v3[d] = __shfl(hn[3], src);
      }
      if (cc < 4) {
        unsigned short hh[4], ll[4]; float4v hf;
        #pragma unroll
        for (int d = 0; d < 4; ++d) {
          float hv = (cc == 0) ? v0[d] : (cc == 1) ? v1[d] : (cc == 2) ? v2[d] : v3[d];
          hf[d] = hv;
          splitHL(hv, hh[d], ll[d]);
        }
        uint4v pk;
        pk[0] = (uint32_t)hh[0] | ((uint32_t)hh[1] << 16);
        pk[1] = (uint32_t)hh[2] | ((uint32_t)hh[3] << 16);
        pk[2] = (uint32_t)ll[0] | ((uint32_t)ll[1] << 16);
        pk[3] = (uint32_t)ll[2] | ((uint32_t)ll[3] << 16);
        // one dwordx4 per lane; 16 lanes -> 256B contiguous = 2 full lines
        uint8_t* dstb = (LAYER ? r1 : r0) + rbyte(slotC, bg, a >> 3)
                      + (size_t)((a >> 2) & 1) * 1024
                      + (size_t)(16 * (a & 3) + 4 * qq + cc) * 16;
        asm volatile("global_store_dwordx4 %0, %1, off sc0 sc1"
                     :: "v"(dstb), "v"(pk) : "memory");
        if (LAYER && t == T_ - 1) {
          float4v* hp = (float4v*)(h1f + (size_t)(bg * 16 + 4 * qq + cc) * H_ + 4 * a);
          asm volatile("global_store_dwordx4 %0, %1, off sc0 sc1"
                       :: "v"(hp), "v"(hf) : "memory");
        }
      }
    }
    if constexpr (FULL) {
      // per-wave drain + flag (kh0), then end-of-step barrier: own-block
      // consumers are ordered by the barrier, so nobody polls own words.
      if (kh == 0) {
        asm volatile("s_waitcnt vmcnt(0)" ::: "memory");
        if (lane == 0)
          __hip_atomic_store(&myprog[bg * 128 + a], (uint32_t)(t + 1),
                             __ATOMIC_RELAXED, __HIP_MEMORY_SCOPE_AGENT);
      }
      __syncthreads();
    } else {
      asm volatile("s_waitcnt vmcnt(0)" ::: "memory");
      __syncthreads();
      if (tid == 0)
        __hip_atomic_store(&myprog[a], (uint32_t)(t + 1),
                           __ATOMIC_RELAXED, __HIP_MEMORY_SCOPE_AGENT);
    }
  }
}

template <bool FULL, bool XPK>
__global__ __launch_bounds__(NTHR_, 2) void lstm_persist(
    const float* __restrict__ x, const uint8_t* __restrict__ xpk,
    const float* __restrict__ Wx0, const float* __restrict__ bx0, const float* __restrict__ Wh0,
    const float* __restrict__ Wx1, const float* __restrict__ bx1, const float* __restrict__ Wh1,
    uint32_t* prog0, uint32_t* prog1,
    uint8_t* ring0, uint8_t* ring1,
    float* h1f)
{
  __shared__ unsigned short Wsh[16384];  // 32 KB: W-hi frags
  __shared__ float red[1024];            // 4 KB: split-K reduction
  if (blockIdx.x < 128)
    run_layer<0, FULL, XPK>(blockIdx.x, x, xpk, Wx0, bx0, Wh0, prog0, prog1,
                            ring0, ring1, h1f, Wsh, red);
  else
    run_layer<1, FULL, XPK>(blockIdx.x - 128, x, xpk, Wx1, bx1, Wh1, prog0, prog1,
                            ring0, ring1, h1f, Wsh, red);
}

// pre-convert x (fp32) into ring-tile fragment layout:
// xpk[t][bg][tile:8][jh:2][lane':64]{hi2 8B|lo2 8B}; element d of lane l,
// plane jh = x[bg*16+(l&15)][t][tile*32 + 4*(l>>4) + 16*jh + d]
__global__ void prep_x(const float* __restrict__ x, uint8_t* __restrict__ xpk)
{
  size_t idx = (size_t)blockIdx.x * blockDim.x + threadIdx.x;
  if (idx >= (size_t)T_ * 4 * 8 * 2 * 64) return;
  int l    = idx & 63;
  int jh   = (idx >> 6) & 1;
  int tile = (idx >> 7) & 7;
  int bg   = (idx >> 10) & 3;
  int t    = (int)(idx >> 12);
  int row  = bg * 16 + (l & 15);
  int k0   = tile * 32 + 4 * (l >> 4) + 16 * jh;
  float4v f = *(const float4v*)(x + ((size_t)row * T_ + t) * I_ + k0);
  unsigned short hh[4], ll[4];
  #pragma unroll
  for (int d = 0; d < 4; ++d) splitHL(f[d], hh[d], ll[d]);
  uint4v pk;
  pk[0] = (uint32_t)hh[0] | ((uint32_t)hh[1] << 16);
  pk[1] = (uint32_t)hh[2] | ((uint32_t)hh[3] << 16);
  pk[2] = (uint32_t)ll[0] | ((uint32_t)ll[1] << 16);
  pk[3] = (uint32_t)ll[2] | ((uint32_t)ll[3] << 16);
  *(uint4v*)(xpk + idx * 16) = pk;
}

__global__ void fc_out(const float* __restrict__ h1f, const float* __restrict__ Wfc,
                       const float* __restrict__ bfc, float* __restrict__ out)
{
  int tid = threadIdx.x;
  int b = tid >> 3, p = tid & 7;
  const float* hp = h1f + (size_t)b * H_ + p * 64;
  const float* wp = Wfc + p * 64;
  float4v hv[16];
  #pragma unroll
  for (int q = 0; q < 16; ++q)
    asm volatile("global_load_dwordx4 %0, %1, off sc0 sc1"
                 : "=&v"(hv[q]) : "v"(hp + 4 * q) : "memory");
  asm volatile("s_waitcnt vmcnt(0)" ::: "memory");
  float s = 0.f;
  #pragma unroll
  for (int q = 0; q < 16; ++q) {
    float4v wv = *(const float4v*)(wp + 4 * q);
    s += hv[q][0] * wv[0] + hv[q][1] * wv[1] + hv[q][2] * wv[2] + hv[q][3] * wv[3];
  }
  s += __shfl_xor(s, 1);
  s += __shfl_xor(s, 2);
  s += __shfl_xor(s, 4);
  if (p == 0) out[b] = s + bfc[0];
}

extern "C" void kernel_launch(void* const* d_in, const int* in_sizes, int n_in,
                              void* d_out, int out_size, void* d_ws, size_t ws_size,
                              hipStream_t stream)
{
  const float* x   = (const float*)d_in[0];
  const float* Wx0 = (const float*)d_in[1];
  const float* bx0 = (const float*)d_in[2];
  const float* Wh0 = (const float*)d_in[3];
  const float* Wx1 = (const float*)d_in[4];
  const float* bx1 = (const float*)d_in[5];
  const float* Wh1 = (const float*)d_in[6];
  const float* Wfc = (const float*)d_in[7];
  const float* bfc = (const float*)d_in[8];

  uint8_t* ws = (uint8_t*)d_ws;
  const size_t RINGB_FULL = (size_t)(T_ + 1) * SLOT_B;     // 65.7 MB per ring
  const size_t RINGB_CYC  = (size_t)D_ * SLOT_B;           // 1 MB per ring
  const size_t XPKB       = (size_t)T_ * 4 * 8 * TILE_B;   // 32 MB
  const size_t H1FB       = (size_t)B_ * H_ * 4;           // 128 KB
  const size_t NEED_FULL  = 4096 + 2 * RINGB_FULL + H1FB;
  const size_t NEED_XPK   = NEED_FULL + XPKB;

  // flags: prog[layer][bg*128+a] -> 2 x 512 u32 = 4 KB
  uint32_t* prog0 = (uint32_t*)ws;
  uint32_t* prog1 = (uint32_t*)(ws + 2048);

  if (ws_size >= NEED_XPK) {
    uint8_t* ring0 = ws + 4096;
    uint8_t* ring1 = ws + 4096 + RINGB_FULL;
    uint8_t* xpk   = ws + 4096 + 2 * RINGB_FULL;
    float* h1f = (float*)(ws + 4096 + 2 * RINGB_FULL + XPKB);
    (void)hipMemsetAsync(ws, 0, 4096 + SLOT_B, stream);   // flags + ring0 slot0
    (void)hipMemsetAsync(ring1, 0, SLOT_B, stream);       // ring1 slot0
    hipLaunchKernelGGL(prep_x, dim3(4096), dim3(512), 0, stream, x, xpk);
    hipLaunchKernelGGL((lstm_persist<true, true>), dim3(256), dim3(NTHR_), 0, stream,
                       x, xpk, Wx0, bx0, Wh0, Wx1, bx1, Wh1,
                       prog0, prog1, ring0, ring1, h1f);
    hipLaunchKernelGGL(fc_out, dim3(1), dim3(512), 0, stream,
                       h1f, Wfc, bfc, (float*)d_out);
  } else if (ws_size >= NEED_FULL) {
    uint8_t* ring0 = ws + 4096;
    uint8_t* ring1 = ws + 4096 + RINGB_FULL;
    float* h1f = (float*)(ws + 4096 + 2 * RINGB_FULL);
    (void)hipMemsetAsync(ws, 0, 4096 + SLOT_B, stream);
    (void)hipMemsetAsync(ring1, 0, SLOT_B, stream);
    hipLaunchKernelGGL((lstm_persist<true, false>), dim3(256), dim3(NTHR_), 0, stream,
                       x, (const uint8_t*)nullptr, Wx0, bx0, Wh0, Wx1, bx1, Wh1,
                       prog0, prog1, ring0, ring1, h1f);
    hipLaunchKernelGGL(fc_out, dim3(1), dim3(512), 0, stream,
                       h1f, Wfc, bfc, (float*)d_out);
  } else {
    uint8_t* ring0 = ws + 4096;
    uint8_t* ring1 = ws + 4096 + RINGB_CYC;
    float* h1f = (float*)(ws + 4096 + 2 * RINGB_CYC);
    (void)hipMemsetAsync(ws, 0, 4096 + 2 * RINGB_CYC, stream);
    hipLaunchKernelGGL((lstm_persist<false, false>), dim3(256), dim3(NTHR_), 0, stream,
                       x, (const uint8_t*)nullptr, Wx0, bx0, Wh0, Wx1, bx1, Wh1,
                       prog0, prog1, ring0, ring1, h1f);
    hipLaunchKernelGGL(fc_out, dim3(1), dim3(512), 0, stream,
                       h1f, Wfc, bfc, (float*)d_out);
  }
}